// Round 1
// baseline (85433.350 us; speedup 1.0000x reference)
//
#include <hip/hip_runtime.h>
#include <hip/hip_bf16.h>
#include <cstdint>
#include <cstddef>

// Problem constants
#define T_LEN 1024
#define B_SZ  64
#define H_DIM 512
#define D_IN  512

// Decomposition: 2 dirs x 4 batch-groups (16 rows each) x 32 col-groups (16 h-cols each)
#define NBG    4
#define GROUP  32          // blocks per (dir,bg) sync group
#define BS     16          // batch rows per group
#define CW     16          // h-cols per block

typedef __attribute__((ext_vector_type(8))) short short8;
typedef __attribute__((ext_vector_type(4))) float f32x4;

// LDS layout (bytes)
#define OFF_WR   0          // 16 rows x 2048B  ([Wih_r | Whh_r], K=1024 bf16)
#define OFF_WZ   32768      // 16 rows x 2048B
#define OFF_WXN  65536      // 16 rows x 1024B  (Wih_n, K=512)
#define OFF_WHN  81920      // 16 rows x 1024B  (Whh_n, K=512)
#define OFF_X    98304      // 16 rows x 1024B  (x_t bf16, K=512)
#define OFF_H    114688     // 16 rows x 1024B  (h_{t-1} bf16, K=512)
#define OFF_D    131072     // 4 tiles x 16x16 f32
#define SMEM_BYTES 135168

__device__ __forceinline__ int swz(int row, int byteoff) {
  // XOR-swizzle 16B granules within a row: breaks the 16-way bank conflict of
  // stride-1024/2048 row-major tiles (guide G4/T2). Same XOR on write and read.
  return byteoff ^ ((row & 7) << 4);
}

__device__ __forceinline__ unsigned short f2bf(float f) {
  unsigned u = __float_as_uint(f);
  unsigned r = (u + 0x7FFFu + ((u >> 16) & 1u)) >> 16;   // RNE
  return (unsigned short)r;
}

__device__ __forceinline__ short8 pack8(float4 a, float4 b) {
  short8 v;
  v[0] = (short)f2bf(a.x); v[1] = (short)f2bf(a.y);
  v[2] = (short)f2bf(a.z); v[3] = (short)f2bf(a.w);
  v[4] = (short)f2bf(b.x); v[5] = (short)f2bf(b.y);
  v[6] = (short)f2bf(b.z); v[7] = (short)f2bf(b.w);
  return v;
}

__device__ __forceinline__ float sigm(float x) { return 1.0f / (1.0f + __expf(-x)); }

__device__ __forceinline__ size_t hidx(int par, int dir, int bg, int row, int col) {
  return ((((size_t)((par * 2 + dir) * NBG + bg)) * BS + row) * H_DIM + col);
}

template<int LAYER>
__global__ __launch_bounds__(256, 1)
void gru_layer(const float* __restrict__ x,
               const float* __restrict__ enc,
               const float* __restrict__ WihF, const float* __restrict__ WhhF,
               const float* __restrict__ bihF, const float* __restrict__ bhhF,
               const float* __restrict__ WihB, const float* __restrict__ WhhB,
               const float* __restrict__ bihB, const float* __restrict__ bhhB,
               float* __restrict__ dout,
               unsigned* __restrict__ ctrs,
               unsigned short* __restrict__ hbuf)
{
  __shared__ alignas(16) char smem[SMEM_BYTES];

  const int bid  = blockIdx.x;
  const int grp  = bid & 7;          // dir*4+bg; with round-robin placement all 32
  const int dir  = grp >> 2;         // blocks of a group share one XCD (perf only)
  const int bg   = grp & 3;
  const int tid  = threadIdx.x;
  const int wv   = tid >> 6;
  const int lane = tid & 63;
  const int lrow = lane & 15;
  const int q    = lane >> 4;
  const int tb   = tid >> 4;         // 0..15 (batch-local row / staging row)
  const int tc   = tid & 15;         // 0..15 (col-local / staging segment)
  const int hc0  = (bid >> 3) * CW;  // this block's h-column base
  const int hcol = hc0 + tc;         // this thread's h column
  const int bglobal = bg * BS + tb;  // this thread's batch row
  const int dircol  = dir * H_DIM;

  const float* Wih = (dir == 0 ? WihF : WihB) + (size_t)LAYER * 3 * H_DIM * D_IN;
  const float* Whh = (dir == 0 ? WhhF : WhhB) + (size_t)LAYER * 3 * H_DIM * H_DIM;
  const float* bih = (dir == 0 ? bihF : bihB) + (size_t)LAYER * 3 * H_DIM;
  const float* bhh = (dir == 0 ? bhhF : bhhB) + (size_t)LAYER * 3 * H_DIM;

  unsigned* ctr = ctrs + (LAYER * 8 + grp);

  // ---- Stage weights into LDS (once). Rows = gate columns [hc0, hc0+16). ----
  {
    // r and z: fused [Wih | Whh] rows of K=1024
    #pragma unroll
    for (int g = 0; g < 2; ++g) {
      const int R = g * H_DIM + hc0 + tb;
      char* ldsrow = smem + (g == 0 ? OFF_WR : OFF_WZ) + tb * 2048;
      const float* src = (tc < 8) ? (Wih + (size_t)R * D_IN + tc * 64)
                                  : (Whh + (size_t)R * H_DIM + (tc - 8) * 64);
      const int kb0 = tc * 128;   // byte base in LDS row (tc*64 bf16)
      #pragma unroll
      for (int u = 0; u < 8; ++u) {
        float4 a = ((const float4*)src)[u * 2];
        float4 b = ((const float4*)src)[u * 2 + 1];
        *(short8*)(ldsrow + swz(tb, kb0 + u * 16)) = pack8(a, b);
      }
    }
    // xn (Wih_n) and hn (Whh_n): K=512 each
    const int R = 2 * H_DIM + hc0 + tb;
    const float* s0 = Wih + (size_t)R * D_IN + tc * 32;
    const float* s1 = Whh + (size_t)R * H_DIM + tc * 32;
    char* r0 = smem + OFF_WXN + tb * 1024;
    char* r1 = smem + OFF_WHN + tb * 1024;
    #pragma unroll
    for (int u = 0; u < 4; ++u) {
      float4 a0 = ((const float4*)s0)[u * 2];
      float4 b0 = ((const float4*)s0)[u * 2 + 1];
      *(short8*)(r0 + swz(tb, tc * 64 + u * 16)) = pack8(a0, b0);
      float4 a1 = ((const float4*)s1)[u * 2];
      float4 b1 = ((const float4*)s1)[u * 2 + 1];
      *(short8*)(r1 + swz(tb, tc * 64 + u * 16)) = pack8(a1, b1);
    }
  }

  // ---- Per-thread biases and initial hidden state ----
  const float b_r  = bih[hcol] + bhh[hcol];
  const float b_z  = bih[H_DIM + hcol] + bhh[H_DIM + hcol];
  const float b_xn = bih[2 * H_DIM + hcol];
  const float b_hn = bhh[2 * H_DIM + hcol];
  float hreg = enc[(size_t)LAYER * B_SZ * 2 * H_DIM + (size_t)bglobal * 2 * H_DIM + dircol + hcol];

  // publish h0 (buffer parity 0), then arrive at the group barrier
  hbuf[hidx(0, dir, bg, tb, hcol)] = f2bf(hreg);
  __threadfence();
  __syncthreads();
  if (tid == 0)
    __hip_atomic_fetch_add(ctr, 1u, __ATOMIC_RELEASE, __HIP_MEMORY_SCOPE_AGENT);

  float yprev = 0.0f;

  for (int t = 0; t < T_LEN; ++t) {
    // ---- group barrier: all 32 blocks finished step t-1 (or init) ----
    if (tid == 0) {
      const unsigned target = (unsigned)GROUP * (unsigned)(t + 1);
      while (__hip_atomic_load(ctr, __ATOMIC_ACQUIRE, __HIP_MEMORY_SCOPE_AGENT) < target)
        __builtin_amdgcn_s_sleep(1);
    }
    __syncthreads();
    __threadfence();

    const int torig = dir ? (T_LEN - 1 - t) : t;

    // layer 1: delayed in-place overwrite of y0[t-1] with y1[t-1] (safe: barrier
    // above guarantees every block in the group finished reading y0[t-1])
    if (LAYER == 1 && t > 0) {
      const int tprev = dir ? (T_LEN - t) : (t - 1);
      dout[(size_t)bglobal * T_LEN * 2 * H_DIM + (size_t)tprev * 2 * H_DIM + dircol + hcol] = yprev;
    }

    // ---- stage x_t (fp32 -> bf16) and h_{t-1} (bf16) into LDS ----
    {
      const float* xrow = (LAYER == 0)
        ? (x + ((size_t)bglobal * T_LEN + torig) * D_IN)
        : (dout + ((size_t)bglobal * T_LEN + torig) * 2 * H_DIM + dircol);
      const float4* s4 = (const float4*)(xrow + tc * 32);
      char* lx = smem + OFF_X + tb * 1024;
      #pragma unroll
      for (int u = 0; u < 4; ++u) {
        float4 a = s4[u * 2];
        float4 b = s4[u * 2 + 1];
        *(short8*)(lx + swz(tb, tc * 64 + u * 16)) = pack8(a, b);
      }
      const short8* hs = (const short8*)(hbuf + hidx(t & 1, dir, bg, tb, 0) + tc * 32);
      char* lh = smem + OFF_H + tb * 1024;
      #pragma unroll
      for (int u = 0; u < 4; ++u) {
        short8 v = hs[u];
        *(short8*)(lh + swz(tb, tc * 64 + u * 16)) = v;
      }
    }
    __syncthreads();

    // ---- MFMA: wave0=r (K=1024), wave1=z (K=1024), wave2=xn, wave3=hn ----
    f32x4 acc = {0.f, 0.f, 0.f, 0.f};
    if (wv < 2) {
      char* wrow = smem + (wv == 0 ? OFF_WR : OFF_WZ) + lrow * 2048;
      char* xr = smem + OFF_X + lrow * 1024;
      char* hr = smem + OFF_H + lrow * 1024;
      #pragma unroll
      for (int kc = 0; kc < 32; ++kc) {
        char* arow = (kc < 16) ? xr : hr;
        short8 a = *(const short8*)(arow + swz(lrow, (kc & 15) * 64 + q * 16));
        short8 b = *(const short8*)(wrow + swz(lrow, kc * 64 + q * 16));
        acc = __builtin_amdgcn_mfma_f32_16x16x32_bf16(a, b, acc, 0, 0, 0);
      }
    } else {
      char* wrow = smem + (wv == 2 ? OFF_WXN : OFF_WHN) + lrow * 1024;
      char* arow = smem + (wv == 2 ? OFF_X : OFF_H) + lrow * 1024;
      #pragma unroll
      for (int kc = 0; kc < 16; ++kc) {
        short8 a = *(const short8*)(arow + swz(lrow, kc * 64 + q * 16));
        short8 b = *(const short8*)(wrow + swz(lrow, kc * 64 + q * 16));
        acc = __builtin_amdgcn_mfma_f32_16x16x32_bf16(a, b, acc, 0, 0, 0);
      }
    }
    {
      float* dt = (float*)(smem + OFF_D + wv * 1024);
      #pragma unroll
      for (int r = 0; r < 4; ++r) dt[(q * 4 + r) * 16 + lrow] = acc[r];
    }
    __syncthreads();

    // ---- elementwise GRU update (one thread = one (batch,hcol) element) ----
    {
      const float* Dr  = (const float*)(smem + OFF_D + 0 * 1024);
      const float* Dz  = (const float*)(smem + OFF_D + 1 * 1024);
      const float* Dxn = (const float*)(smem + OFF_D + 2 * 1024);
      const float* Dhn = (const float*)(smem + OFF_D + 3 * 1024);
      const int e = tb * 16 + tc;
      const float r = sigm(Dr[e] + b_r);
      const float z = sigm(Dz[e] + b_z);
      const float n = tanhf(Dxn[e] + b_xn + r * (Dhn[e] + b_hn));
      const float hnew = (1.0f - z) * n + z * hreg;
      hreg = hnew;
      hbuf[hidx((t + 1) & 1, dir, bg, tb, hcol)] = f2bf(hnew);
      if (LAYER == 0) {
        dout[(size_t)bglobal * T_LEN * 2 * H_DIM + (size_t)torig * 2 * H_DIM + dircol + hcol] = hnew;
      } else {
        yprev = hnew;
      }
      if (t == T_LEN - 1) {
        dout[(size_t)B_SZ * T_LEN * 2 * H_DIM +
             ((size_t)LAYER * B_SZ + bglobal) * 2 * H_DIM + dircol + hcol] = hnew;
      }
    }

    __threadfence();
    __syncthreads();
    if (tid == 0)
      __hip_atomic_fetch_add(ctr, 1u, __ATOMIC_RELEASE, __HIP_MEMORY_SCOPE_AGENT);
  }

  // layer 1: flush the last delayed output (after everyone finished step T-1)
  if (LAYER == 1) {
    if (tid == 0) {
      const unsigned target = (unsigned)GROUP * (unsigned)(T_LEN + 1);
      while (__hip_atomic_load(ctr, __ATOMIC_ACQUIRE, __HIP_MEMORY_SCOPE_AGENT) < target)
        __builtin_amdgcn_s_sleep(1);
    }
    __syncthreads();
    __threadfence();
    const int tlast = dir ? 0 : (T_LEN - 1);
    dout[(size_t)bglobal * T_LEN * 2 * H_DIM + (size_t)tlast * 2 * H_DIM + dircol + hcol] = yprev;
  }
}

extern "C" void kernel_launch(void* const* d_in, const int* in_sizes, int n_in,
                              void* d_out, int out_size, void* d_ws, size_t ws_size,
                              hipStream_t stream) {
  (void)in_sizes; (void)n_in; (void)out_size; (void)ws_size;
  const float* x    = (const float*)d_in[0];
  const float* enc  = (const float*)d_in[1];
  const float* WihF = (const float*)d_in[2];
  const float* WhhF = (const float*)d_in[3];
  const float* bihF = (const float*)d_in[4];
  const float* bhhF = (const float*)d_in[5];
  const float* WihB = (const float*)d_in[6];
  const float* WhhB = (const float*)d_in[7];
  const float* bihB = (const float*)d_in[8];
  const float* bhhB = (const float*)d_in[9];
  float* out = (float*)d_out;

  unsigned* ctrs = (unsigned*)d_ws;
  unsigned short* hbuf = (unsigned short*)((char*)d_ws + 1024);
  // zero the barrier counters (captured into the graph; re-runs each replay)
  hipMemsetAsync(d_ws, 0, 1024, stream);

  dim3 grid(GROUP * 8), block(256);
  gru_layer<0><<<grid, block, 0, stream>>>(x, enc, WihF, WhhF, bihF, bhhF,
                                           WihB, WhhB, bihB, bhhB, out, ctrs, hbuf);
  gru_layer<1><<<grid, block, 0, stream>>>(x, enc, WihF, WhhF, bihF, bhhF,
                                           WihB, WhhB, bihB, bhhB, out, ctrs, hbuf);
}

// Round 2
// 9928.123 us; speedup vs baseline: 8.6052x; 8.6052x over previous
//
#include <hip/hip_runtime.h>
#include <hip/hip_bf16.h>
#include <cstdint>
#include <cstddef>

// Problem constants
#define T_LEN 1024
#define B_SZ  64
#define H_DIM 512
#define D_IN  512

// Decomposition: 2 dirs x 4 batch-groups (16 rows each) x 32 col-groups (16 h-cols each)
#define NBG    4
#define GROUP  32          // blocks per (dir,bg) sync group
#define BS     16          // batch rows per group
#define CW     16          // h-cols per block

typedef __attribute__((ext_vector_type(8))) short short8;
typedef __attribute__((ext_vector_type(4))) float f32x4;

// LDS layout (bytes)
#define OFF_WR   0          // 16 rows x 2048B  ([Wih_r | Whh_r], K=1024 bf16)
#define OFF_WZ   32768      // 16 rows x 2048B
#define OFF_WXN  65536      // 16 rows x 1024B  (Wih_n, K=512)
#define OFF_WHN  81920      // 16 rows x 1024B  (Whh_n, K=512)
#define OFF_X    98304      // 16 rows x 1024B  (x_t bf16, K=512)
#define OFF_H    114688     // 16 rows x 1024B  (h_{t-1} bf16, K=512)
#define OFF_D    131072     // 4 tiles x 16x16 f32
#define SMEM_BYTES 135168

__device__ __forceinline__ int swz(int row, int byteoff) {
  // XOR-swizzle 16B granules within a row (breaks stride-1024/2048 conflicts).
  return byteoff ^ ((row & 7) << 4);
}

__device__ __forceinline__ unsigned short f2bf(float f) {
  unsigned u = __float_as_uint(f);
  unsigned r = (u + 0x7FFFu + ((u >> 16) & 1u)) >> 16;   // RNE
  return (unsigned short)r;
}

__device__ __forceinline__ short8 pack8(float4 a, float4 b) {
  short8 v;
  v[0] = (short)f2bf(a.x); v[1] = (short)f2bf(a.y);
  v[2] = (short)f2bf(a.z); v[3] = (short)f2bf(a.w);
  v[4] = (short)f2bf(b.x); v[5] = (short)f2bf(b.y);
  v[6] = (short)f2bf(b.z); v[7] = (short)f2bf(b.w);
  return v;
}

__device__ __forceinline__ float sigm(float x) { return 1.0f / (1.0f + __expf(-x)); }

__device__ __forceinline__ size_t hidx(int par, int dir, int bg, int row, int col) {
  return ((((size_t)((par * 2 + dir) * NBG + bg)) * BS + row) * H_DIM + col);
}

template<int LAYER>
__global__ __launch_bounds__(256, 1)
void gru_layer(const float* __restrict__ x,
               const float* __restrict__ enc,
               const float* __restrict__ WihF, const float* __restrict__ WhhF,
               const float* __restrict__ bihF, const float* __restrict__ bhhF,
               const float* __restrict__ WihB, const float* __restrict__ WhhB,
               const float* __restrict__ bihB, const float* __restrict__ bhhB,
               float* __restrict__ dout,
               unsigned* __restrict__ ctrs,
               unsigned short* __restrict__ hbuf)
{
  __shared__ alignas(16) char smem[SMEM_BYTES];

  const int bid  = blockIdx.x;
  const int grp  = bid & 7;          // dir*4+bg
  const int dir  = grp >> 2;
  const int bg   = grp & 3;
  const int tid  = threadIdx.x;
  const int wv   = tid >> 6;
  const int lane = tid & 63;
  const int lrow = lane & 15;
  const int q    = lane >> 4;
  const int tb   = tid >> 4;         // 0..15 (batch-local row / staging row)
  const int tc   = tid & 15;         // 0..15 (col-local / staging segment)
  const int hc0  = (bid >> 3) * CW;  // this block's h-column base
  const int hcol = hc0 + tc;         // this thread's h column
  const int bglobal = bg * BS + tb;  // this thread's batch row
  const int dircol  = dir * H_DIM;

  const float* Wih = (dir == 0 ? WihF : WihB) + (size_t)LAYER * 3 * H_DIM * D_IN;
  const float* Whh = (dir == 0 ? WhhF : WhhB) + (size_t)LAYER * 3 * H_DIM * H_DIM;
  const float* bih = (dir == 0 ? bihF : bihB) + (size_t)LAYER * 3 * H_DIM;
  const float* bhh = (dir == 0 ? bhhF : bhhB) + (size_t)LAYER * 3 * H_DIM;

  // padded barrier counters: one 256B line per (layer,group)
  unsigned* ctr = ctrs + (LAYER * 8 + grp) * 64;

  // ---- Stage weights into LDS (once). Rows = gate columns [hc0, hc0+16). ----
  {
    #pragma unroll
    for (int g = 0; g < 2; ++g) {
      const int R = g * H_DIM + hc0 + tb;
      char* ldsrow = smem + (g == 0 ? OFF_WR : OFF_WZ) + tb * 2048;
      const float* src = (tc < 8) ? (Wih + (size_t)R * D_IN + tc * 64)
                                  : (Whh + (size_t)R * H_DIM + (tc - 8) * 64);
      const int kb0 = tc * 128;
      #pragma unroll
      for (int u = 0; u < 8; ++u) {
        float4 a = ((const float4*)src)[u * 2];
        float4 b = ((const float4*)src)[u * 2 + 1];
        *(short8*)(ldsrow + swz(tb, kb0 + u * 16)) = pack8(a, b);
      }
    }
    const int R = 2 * H_DIM + hc0 + tb;
    const float* s0 = Wih + (size_t)R * D_IN + tc * 32;
    const float* s1 = Whh + (size_t)R * H_DIM + tc * 32;
    char* r0 = smem + OFF_WXN + tb * 1024;
    char* r1 = smem + OFF_WHN + tb * 1024;
    #pragma unroll
    for (int u = 0; u < 4; ++u) {
      float4 a0 = ((const float4*)s0)[u * 2];
      float4 b0 = ((const float4*)s0)[u * 2 + 1];
      *(short8*)(r0 + swz(tb, tc * 64 + u * 16)) = pack8(a0, b0);
      float4 a1 = ((const float4*)s1)[u * 2];
      float4 b1 = ((const float4*)s1)[u * 2 + 1];
      *(short8*)(r1 + swz(tb, tc * 64 + u * 16)) = pack8(a1, b1);
    }
  }

  // ---- Per-thread biases and initial hidden state ----
  const float b_r  = bih[hcol] + bhh[hcol];
  const float b_z  = bih[H_DIM + hcol] + bhh[H_DIM + hcol];
  const float b_xn = bih[2 * H_DIM + hcol];
  const float b_hn = bhh[2 * H_DIM + hcol];
  float hreg = enc[(size_t)LAYER * B_SZ * 2 * H_DIM + (size_t)bglobal * 2 * H_DIM + dircol + hcol];

  // ---- publish h0 (parity 0) via packed 8B agent-scope stores (sc1, no fence) ----
  {
    unsigned v = f2bf(hreg);
    unsigned v1 = __shfl_down(v, 1);
    unsigned v2 = __shfl_down(v, 2);
    unsigned v3 = __shfl_down(v, 3);
    if ((tc & 3) == 0) {
      unsigned long long pk = (unsigned long long)v | ((unsigned long long)v1 << 16)
                            | ((unsigned long long)v2 << 32) | ((unsigned long long)v3 << 48);
      __hip_atomic_store((unsigned long long*)&hbuf[hidx(0, dir, bg, tb, hcol)], pk,
                         __ATOMIC_RELAXED, __HIP_MEMORY_SCOPE_AGENT);
    }
  }
  asm volatile("s_waitcnt vmcnt(0)" ::: "memory");
  __syncthreads();
  if (tid == 0)
    __hip_atomic_fetch_add(ctr, 1u, __ATOMIC_RELAXED, __HIP_MEMORY_SCOPE_AGENT);

  float yprev = 0.0f;

  for (int t = 0; t < T_LEN; ++t) {
    const int torig = dir ? (T_LEN - 1 - t) : t;

    // ---- stage x_t into LDS BEFORE the barrier (x never depends on h). For
    // LAYER 1 this reads layer-0 output; concurrent in-place overwrites only
    // target indices strictly behind torig, so this prefetch is race-free. ----
    {
      const float* xrow = (LAYER == 0)
        ? (x + ((size_t)bglobal * T_LEN + torig) * D_IN)
        : (dout + ((size_t)bglobal * T_LEN + torig) * 2 * H_DIM + dircol);
      const float4* s4 = (const float4*)(xrow + tc * 32);
      char* lx = smem + OFF_X + tb * 1024;
      #pragma unroll
      for (int u = 0; u < 4; ++u) {
        float4 a = s4[u * 2];
        float4 b = s4[u * 2 + 1];
        *(short8*)(lx + swz(tb, tc * 64 + u * 16)) = pack8(a, b);
      }
    }

    // ---- group barrier: all 32 blocks finished step t-1 (relaxed spin, sc1) ----
    if (tid == 0) {
      const unsigned target = (unsigned)GROUP * (unsigned)(t + 1);
      while (__hip_atomic_load(ctr, __ATOMIC_RELAXED, __HIP_MEMORY_SCOPE_AGENT) < target)
        __builtin_amdgcn_s_sleep(1);
    }
    __syncthreads();

    // layer 1: delayed in-place overwrite of y0[t-1] with y1[t-1] (safe: barrier
    // above guarantees every block in the group finished reading y0[t-1])
    if (LAYER == 1 && t > 0) {
      const int tprev = dir ? (T_LEN - t) : (t - 1);
      dout[(size_t)bglobal * T_LEN * 2 * H_DIM + (size_t)tprev * 2 * H_DIM + dircol + hcol] = yprev;
    }

    // ---- stage h_{t-1} from hbuf (packed 8B agent-scope loads, bypass L2) ----
    {
      const unsigned long long* hb =
        (const unsigned long long*)(hbuf + hidx(t & 1, dir, bg, tb, 0) + tc * 32);
      char* lh = smem + OFF_H + tb * 1024;
      #pragma unroll
      for (int u = 0; u < 4; ++u) {
        unsigned long long lo = __hip_atomic_load(hb + u * 2,     __ATOMIC_RELAXED, __HIP_MEMORY_SCOPE_AGENT);
        unsigned long long hi = __hip_atomic_load(hb + u * 2 + 1, __ATOMIC_RELAXED, __HIP_MEMORY_SCOPE_AGENT);
        unsigned long long tmp[2] = {lo, hi};
        *(short8*)(lh + swz(tb, tc * 64 + u * 16)) = *(const short8*)tmp;
      }
    }
    __syncthreads();

    // ---- MFMA: wave0=r (K=1024), wave1=z (K=1024), wave2=xn, wave3=hn ----
    f32x4 acc = {0.f, 0.f, 0.f, 0.f};
    if (wv < 2) {
      char* wrow = smem + (wv == 0 ? OFF_WR : OFF_WZ) + lrow * 2048;
      char* xr = smem + OFF_X + lrow * 1024;
      char* hr = smem + OFF_H + lrow * 1024;
      #pragma unroll
      for (int kc = 0; kc < 32; ++kc) {
        char* arow = (kc < 16) ? xr : hr;
        short8 a = *(const short8*)(arow + swz(lrow, (kc & 15) * 64 + q * 16));
        short8 b = *(const short8*)(wrow + swz(lrow, kc * 64 + q * 16));
        acc = __builtin_amdgcn_mfma_f32_16x16x32_bf16(a, b, acc, 0, 0, 0);
      }
    } else {
      char* wrow = smem + (wv == 2 ? OFF_WXN : OFF_WHN) + lrow * 1024;
      char* arow = smem + (wv == 2 ? OFF_X : OFF_H) + lrow * 1024;
      #pragma unroll
      for (int kc = 0; kc < 16; ++kc) {
        short8 a = *(const short8*)(arow + swz(lrow, kc * 64 + q * 16));
        short8 b = *(const short8*)(wrow + swz(lrow, kc * 64 + q * 16));
        acc = __builtin_amdgcn_mfma_f32_16x16x32_bf16(a, b, acc, 0, 0, 0);
      }
    }
    {
      // de-conflicted D-tile write: permute col by +4q within the 16-col row
      float* dt = (float*)(smem + OFF_D + wv * 1024);
      #pragma unroll
      for (int r = 0; r < 4; ++r)
        dt[(q * 4 + r) * 16 + ((lrow + 4 * q) & 15)] = acc[r];
    }
    __syncthreads();

    // ---- elementwise GRU update (one thread = one (batch,hcol) element) ----
    {
      const float* Dr  = (const float*)(smem + OFF_D + 0 * 1024);
      const float* Dz  = (const float*)(smem + OFF_D + 1 * 1024);
      const float* Dxn = (const float*)(smem + OFF_D + 2 * 1024);
      const float* Dhn = (const float*)(smem + OFF_D + 3 * 1024);
      const int e = tb * 16 + ((tc + 4 * (tb >> 2)) & 15);
      const float r = sigm(Dr[e] + b_r);
      const float z = sigm(Dz[e] + b_z);
      const float n = tanhf(Dxn[e] + b_xn + r * (Dhn[e] + b_hn));
      const float hnew = (1.0f - z) * n + z * hreg;
      hreg = hnew;

      // publish h_t (packed 8B agent-scope stores)
      unsigned v = f2bf(hnew);
      unsigned v1 = __shfl_down(v, 1);
      unsigned v2 = __shfl_down(v, 2);
      unsigned v3 = __shfl_down(v, 3);
      if ((tc & 3) == 0) {
        unsigned long long pk = (unsigned long long)v | ((unsigned long long)v1 << 16)
                              | ((unsigned long long)v2 << 32) | ((unsigned long long)v3 << 48);
        __hip_atomic_store((unsigned long long*)&hbuf[hidx((t + 1) & 1, dir, bg, tb, hcol)], pk,
                           __ATOMIC_RELAXED, __HIP_MEMORY_SCOPE_AGENT);
      }

      if (LAYER == 0) {
        dout[(size_t)bglobal * T_LEN * 2 * H_DIM + (size_t)torig * 2 * H_DIM + dircol + hcol] = hnew;
      } else {
        yprev = hnew;
      }
      if (t == T_LEN - 1) {
        dout[(size_t)B_SZ * T_LEN * 2 * H_DIM +
             ((size_t)LAYER * B_SZ + bglobal) * 2 * H_DIM + dircol + hcol] = hnew;
      }
    }

    // drain our stores (sc1 stores are globally visible once vmcnt retires),
    // then post arrival — no L2 writeback fence anywhere.
    asm volatile("s_waitcnt vmcnt(0)" ::: "memory");
    __syncthreads();
    if (tid == 0)
      __hip_atomic_fetch_add(ctr, 1u, __ATOMIC_RELAXED, __HIP_MEMORY_SCOPE_AGENT);
  }

  // layer 1: flush the last delayed output (after everyone finished step T-1)
  if (LAYER == 1) {
    if (tid == 0) {
      const unsigned target = (unsigned)GROUP * (unsigned)(T_LEN + 1);
      while (__hip_atomic_load(ctr, __ATOMIC_RELAXED, __HIP_MEMORY_SCOPE_AGENT) < target)
        __builtin_amdgcn_s_sleep(1);
    }
    __syncthreads();
    const int tlast = dir ? 0 : (T_LEN - 1);
    dout[(size_t)bglobal * T_LEN * 2 * H_DIM + (size_t)tlast * 2 * H_DIM + dircol + hcol] = yprev;
  }
}

extern "C" void kernel_launch(void* const* d_in, const int* in_sizes, int n_in,
                              void* d_out, int out_size, void* d_ws, size_t ws_size,
                              hipStream_t stream) {
  (void)in_sizes; (void)n_in; (void)out_size; (void)ws_size;
  const float* x    = (const float*)d_in[0];
  const float* enc  = (const float*)d_in[1];
  const float* WihF = (const float*)d_in[2];
  const float* WhhF = (const float*)d_in[3];
  const float* bihF = (const float*)d_in[4];
  const float* bhhF = (const float*)d_in[5];
  const float* WihB = (const float*)d_in[6];
  const float* WhhB = (const float*)d_in[7];
  const float* bihB = (const float*)d_in[8];
  const float* bhhB = (const float*)d_in[9];
  float* out = (float*)d_out;

  unsigned* ctrs = (unsigned*)d_ws;                       // 16 x 256B padded lines
  unsigned short* hbuf = (unsigned short*)((char*)d_ws + 4096);
  hipMemsetAsync(d_ws, 0, 4096, stream);                  // zero barrier counters

  dim3 grid(GROUP * 8), block(256);
  gru_layer<0><<<grid, block, 0, stream>>>(x, enc, WihF, WhhF, bihF, bhhF,
                                           WihB, WhhB, bihB, bhhB, out, ctrs, hbuf);
  gru_layer<1><<<grid, block, 0, stream>>>(x, enc, WihF, WhhF, bihF, bhhF,
                                           WihB, WhhB, bihB, bhhB, out, ctrs, hbuf);
}

// Round 3
// 9330.434 us; speedup vs baseline: 9.1564x; 1.0641x over previous
//
#include <hip/hip_runtime.h>
#include <hip/hip_bf16.h>
#include <cstdint>
#include <cstddef>

// Problem constants
#define T_LEN 1024
#define B_SZ  64
#define H_DIM 512
#define D_IN  512

// Decomposition: 2 dirs x 4 batch-groups (16 rows each) x 32 col-groups (16 h-cols each)
#define NBG    4
#define GROUP  32          // blocks per (dir,bg) sync group
#define BS     16          // batch rows per group
#define CW     16          // h-cols per block

typedef __attribute__((ext_vector_type(8))) short short8;
typedef __attribute__((ext_vector_type(4))) float f32x4;

// LDS layout (bytes)
#define OFF_WIH  0          // 3 tiles x 16 rows x 1024B  (Wih r/z/n, K=512)
#define OFF_WHH  49152      // 3 tiles x 16 rows x 1024B  (Whh r/z/n, K=512)
#define OFF_X    98304      // 16 rows x 1024B  (x_t bf16)
#define OFF_H    114688     // 16 rows x 1024B  (h_{t-1} bf16)
#define OFF_D    131072     // 5 tiles x 16x16 f32 (Dr, Dz, Dxn, Dhn_a, Dhn_b)
#define SMEM_BYTES 136192

__device__ __forceinline__ int swz(int row, int byteoff) {
  // XOR-swizzle 16B granules within a row (breaks stride-1024 conflicts).
  return byteoff ^ ((row & 7) << 4);
}

__device__ __forceinline__ unsigned short f2bf(float f) {
  unsigned u = __float_as_uint(f);
  return (unsigned short)((u + 0x7FFFu + ((u >> 16) & 1u)) >> 16);   // RNE
}

__device__ __forceinline__ short8 pack8(float4 a, float4 b) {
  short8 v;
  v[0] = (short)f2bf(a.x); v[1] = (short)f2bf(a.y);
  v[2] = (short)f2bf(a.z); v[3] = (short)f2bf(a.w);
  v[4] = (short)f2bf(b.x); v[5] = (short)f2bf(b.y);
  v[6] = (short)f2bf(b.z); v[7] = (short)f2bf(b.w);
  return v;
}

__device__ __forceinline__ float sigm(float x) { return 1.0f / (1.0f + __expf(-x)); }
__device__ __forceinline__ float fast_tanh(float x) { return 1.0f - 2.0f / (__expf(2.0f * x) + 1.0f); }

__device__ __forceinline__ size_t hidx(int par, int dir, int bg, int row, int col) {
  return ((((size_t)((par * 2 + dir) * NBG + bg)) * BS + row) * H_DIM + col);
}

template<int LAYER>
__global__ __launch_bounds__(256, 1)
void gru_layer(const float* __restrict__ x,
               const float* __restrict__ enc,
               const float* __restrict__ WihF, const float* __restrict__ WhhF,
               const float* __restrict__ bihF, const float* __restrict__ bhhF,
               const float* __restrict__ WihB, const float* __restrict__ WhhB,
               const float* __restrict__ bihB, const float* __restrict__ bhhB,
               float* dout,
               unsigned* __restrict__ flags,
               unsigned short* __restrict__ hbuf)
{
  __shared__ alignas(16) char smem[SMEM_BYTES];

  const int bid  = blockIdx.x;
  const int grp  = bid & 7;          // dir*4+bg
  const int dir  = grp >> 2;
  const int bg   = grp & 3;
  const int cg   = bid >> 3;         // col-group id within the group (0..31)
  const int tid  = threadIdx.x;
  const int wv   = tid >> 6;
  const int tb   = tid >> 4;         // 0..15 (batch-local row / staging row)
  const int tc   = tid & 15;         // 0..15 (col-local / staging segment)
  const int lrow = tc;               // MFMA fragment row (= lane&15)
  const int q    = tb & 3;           // MFMA k-quarter (= lane>>4)
  const int hc0  = cg * CW;          // this block's h-column base
  const int hcol = hc0 + tc;
  const int bglobal = bg * BS + tb;
  const int dircol  = dir * H_DIM;

  const float* Wih = (dir == 0 ? WihF : WihB) + (size_t)LAYER * 3 * H_DIM * D_IN;
  const float* Whh = (dir == 0 ? WhhF : WhhB) + (size_t)LAYER * 3 * H_DIM * H_DIM;
  const float* bih = (dir == 0 ? bihF : bihB) + (size_t)LAYER * 3 * H_DIM;
  const float* bhh = (dir == 0 ? bhhF : bhhB) + (size_t)LAYER * 3 * H_DIM;

  unsigned* fl = flags + (LAYER * 8 + grp) * 64;   // 32 producer flags, 256B region

  // ---- Stage weights into LDS (once): 6 tiles of 16 rows x 512 K bf16 ----
  #pragma unroll
  for (int g = 0; g < 3; ++g) {
    const float* s0 = Wih + (size_t)(g * H_DIM + hc0 + tb) * D_IN  + tc * 32;
    const float* s1 = Whh + (size_t)(g * H_DIM + hc0 + tb) * H_DIM + tc * 32;
    char* r0 = smem + OFF_WIH + g * 16384 + tb * 1024;
    char* r1 = smem + OFF_WHH + g * 16384 + tb * 1024;
    #pragma unroll
    for (int u = 0; u < 4; ++u) {
      float4 a0 = ((const float4*)s0)[u * 2];
      float4 b0 = ((const float4*)s0)[u * 2 + 1];
      *(short8*)(r0 + swz(tb, tc * 64 + u * 16)) = pack8(a0, b0);
      float4 a1 = ((const float4*)s1)[u * 2];
      float4 b1 = ((const float4*)s1)[u * 2 + 1];
      *(short8*)(r1 + swz(tb, tc * 64 + u * 16)) = pack8(a1, b1);
    }
  }

  // ---- Per-thread biases and initial hidden state ----
  const float b_r  = bih[hcol] + bhh[hcol];
  const float b_z  = bih[H_DIM + hcol] + bhh[H_DIM + hcol];
  const float b_xn = bih[2 * H_DIM + hcol];
  const float b_hn = bhh[2 * H_DIM + hcol];
  float hreg = enc[(size_t)LAYER * B_SZ * 2 * H_DIM + (size_t)bglobal * 2 * H_DIM + dircol + hcol];

  // ---- publish h0 (parity 0): packed 8B agent-scope stores, then flag=1 ----
  {
    unsigned v = f2bf(hreg);
    unsigned v1 = __shfl_down(v, 1);
    unsigned v2 = __shfl_down(v, 2);
    unsigned v3 = __shfl_down(v, 3);
    if ((tc & 3) == 0) {
      unsigned long long pk = (unsigned long long)v | ((unsigned long long)v1 << 16)
                            | ((unsigned long long)v2 << 32) | ((unsigned long long)v3 << 48);
      __hip_atomic_store((unsigned long long*)&hbuf[hidx(0, dir, bg, tb, hcol)], pk,
                         __ATOMIC_RELAXED, __HIP_MEMORY_SCOPE_AGENT);
    }
  }
  asm volatile("s_waitcnt vmcnt(0)" ::: "memory");
  __syncthreads();   // also covers weight-staging LDS writes
  if (tid == 0)
    __hip_atomic_store(&fl[cg], 1u, __ATOMIC_RELAXED, __HIP_MEMORY_SCOPE_AGENT);

  // ---- persistent accumulators; prologue: stage x(0) + x-part for t=0 ----
  f32x4 acc_main = {0.f, 0.f, 0.f, 0.f};   // w0: r, w1: z, w2: xn
  {
    const int t0 = dir ? (T_LEN - 1) : 0;
    const float* xrow = (LAYER == 0)
      ? (x + ((size_t)bglobal * T_LEN + t0) * D_IN)
      : (dout + ((size_t)bglobal * T_LEN + t0) * 2 * H_DIM + dircol);
    const float4* s4 = (const float4*)(xrow + tc * 32);
    char* lx = smem + OFF_X + tb * 1024;
    #pragma unroll
    for (int u = 0; u < 4; ++u) {
      float4 a = s4[u * 2];
      float4 b = s4[u * 2 + 1];
      *(short8*)(lx + swz(tb, tc * 64 + u * 16)) = pack8(a, b);
    }
    __syncthreads();
    if (wv < 3) {
      char* wrow = smem + OFF_WIH + wv * 16384 + lrow * 1024;
      char* xr   = smem + OFF_X + lrow * 1024;
      #pragma unroll
      for (int kc = 0; kc < 16; ++kc) {
        short8 a = *(const short8*)(xr   + swz(lrow, kc * 64 + q * 16));
        short8 b = *(const short8*)(wrow + swz(lrow, kc * 64 + q * 16));
        acc_main = __builtin_amdgcn_mfma_f32_16x16x32_bf16(a, b, acc_main, 0, 0, 0);
      }
    }
  }

  float yprev = 0.0f;

  for (int t = 0; t < T_LEN; ++t) {
    const int torig = dir ? (T_LEN - 1 - t) : t;

    // ---- wait: all 32 producers published h for this step ----
    if (tid < 32) {
      const unsigned tgt = (unsigned)(t + 1);
      while (__hip_atomic_load(&fl[tid], __ATOMIC_RELAXED, __HIP_MEMORY_SCOPE_AGENT) < tgt)
        __builtin_amdgcn_s_sleep(1);
    }
    __syncthreads();

    // ---- gather h_{t-1}: issue loads, overlap the delayed y1 store ----
    unsigned long long hv[8];
    {
      const unsigned long long* hb =
        (const unsigned long long*)(hbuf + hidx(t & 1, dir, bg, tb, 0) + tc * 32);
      #pragma unroll
      for (int u = 0; u < 8; ++u)
        hv[u] = __hip_atomic_load(hb + u, __ATOMIC_RELAXED, __HIP_MEMORY_SCOPE_AGENT);
    }
    // layer 1: delayed in-place overwrite of y0[t-1] with y1[t-1] (safe: flag
    // t+1 from every block implies it consumed x at that position)
    if (LAYER == 1 && t > 0) {
      const int tprev = dir ? (T_LEN - t) : (t - 1);
      dout[(size_t)bglobal * T_LEN * 2 * H_DIM + (size_t)tprev * 2 * H_DIM + dircol + hcol] = yprev;
    }
    {
      char* lh = smem + OFF_H + tb * 1024;
      #pragma unroll
      for (int u = 0; u < 4; ++u) {
        unsigned long long tmp[2] = {hv[u * 2], hv[u * 2 + 1]};
        *(short8*)(lh + swz(tb, tc * 64 + u * 16)) = *(const short8*)tmp;
      }
    }
    __syncthreads();

    // ---- on-chain h-part MFMAs: w0 r(16), w1 z(16), w2 hn[0..7], w3 hn[8..15] ----
    f32x4 acc_hn = {0.f, 0.f, 0.f, 0.f};
    if (wv < 2) {
      char* wrow = smem + OFF_WHH + wv * 16384 + lrow * 1024;
      char* hr   = smem + OFF_H + lrow * 1024;
      #pragma unroll
      for (int kc = 0; kc < 16; ++kc) {
        short8 a = *(const short8*)(hr   + swz(lrow, kc * 64 + q * 16));
        short8 b = *(const short8*)(wrow + swz(lrow, kc * 64 + q * 16));
        acc_main = __builtin_amdgcn_mfma_f32_16x16x32_bf16(a, b, acc_main, 0, 0, 0);
      }
    } else {
      char* wrow = smem + OFF_WHH + 2 * 16384 + lrow * 1024;
      char* hr   = smem + OFF_H + lrow * 1024;
      const int k0 = (wv == 2) ? 0 : 8;
      #pragma unroll
      for (int kc = 0; kc < 8; ++kc) {
        short8 a = *(const short8*)(hr   + swz(lrow, (k0 + kc) * 64 + q * 16));
        short8 b = *(const short8*)(wrow + swz(lrow, (k0 + kc) * 64 + q * 16));
        acc_hn = __builtin_amdgcn_mfma_f32_16x16x32_bf16(a, b, acc_hn, 0, 0, 0);
      }
    }
    {
      // de-conflicted D-tile writes (permuted col)
      if (wv < 3) {
        float* dt = (float*)(smem + OFF_D + wv * 1024);
        #pragma unroll
        for (int r = 0; r < 4; ++r)
          dt[(q * 4 + r) * 16 + ((lrow + 4 * q) & 15)] = acc_main[r];
      }
      if (wv >= 2) {
        float* dt = (float*)(smem + OFF_D + (wv + 1) * 1024);
        #pragma unroll
        for (int r = 0; r < 4; ++r)
          dt[(q * 4 + r) * 16 + ((lrow + 4 * q) & 15)] = acc_hn[r];
      }
    }
    __syncthreads();

    // ---- elementwise GRU update + immediate h publish ----
    float hnew;
    {
      const float* Dr  = (const float*)(smem + OFF_D + 0 * 1024);
      const float* Dz  = (const float*)(smem + OFF_D + 1 * 1024);
      const float* Dxn = (const float*)(smem + OFF_D + 2 * 1024);
      const float* Dha = (const float*)(smem + OFF_D + 3 * 1024);
      const float* Dhb = (const float*)(smem + OFF_D + 4 * 1024);
      const int e = tb * 16 + ((tc + 4 * (tb >> 2)) & 15);
      const float r = sigm(Dr[e] + b_r);
      const float z = sigm(Dz[e] + b_z);
      const float n = fast_tanh(Dxn[e] + b_xn + r * (Dha[e] + Dhb[e] + b_hn));
      hnew = (1.0f - z) * n + z * hreg;
      hreg = hnew;

      unsigned v = f2bf(hnew);
      unsigned v1 = __shfl_down(v, 1);
      unsigned v2 = __shfl_down(v, 2);
      unsigned v3 = __shfl_down(v, 3);
      if ((tc & 3) == 0) {
        unsigned long long pk = (unsigned long long)v | ((unsigned long long)v1 << 16)
                              | ((unsigned long long)v2 << 32) | ((unsigned long long)v3 << 48);
        __hip_atomic_store((unsigned long long*)&hbuf[hidx((t + 1) & 1, dir, bg, tb, hcol)], pk,
                           __ATOMIC_RELAXED, __HIP_MEMORY_SCOPE_AGENT);
      }
    }
    asm volatile("s_waitcnt vmcnt(0)" ::: "memory");
    __syncthreads();
    if (tid == 0)
      __hip_atomic_store(&fl[cg], (unsigned)(t + 2), __ATOMIC_RELAXED, __HIP_MEMORY_SCOPE_AGENT);

    // ---- off-chain: y store, final h, stage x(t+1), x-part for t+1 ----
    if (LAYER == 0) {
      dout[(size_t)bglobal * T_LEN * 2 * H_DIM + (size_t)torig * 2 * H_DIM + dircol + hcol] = hnew;
    } else {
      yprev = hnew;
    }
    if (t == T_LEN - 1) {
      dout[(size_t)B_SZ * T_LEN * 2 * H_DIM +
           ((size_t)LAYER * B_SZ + bglobal) * 2 * H_DIM + dircol + hcol] = hnew;
    }

    if (t + 1 < T_LEN) {
      const int tnext = dir ? (T_LEN - 2 - t) : (t + 1);
      const float* xrow = (LAYER == 0)
        ? (x + ((size_t)bglobal * T_LEN + tnext) * D_IN)
        : (dout + ((size_t)bglobal * T_LEN + tnext) * 2 * H_DIM + dircol);
      const float4* s4 = (const float4*)(xrow + tc * 32);
      char* lx = smem + OFF_X + tb * 1024;
      #pragma unroll
      for (int u = 0; u < 4; ++u) {
        float4 a = s4[u * 2];
        float4 b = s4[u * 2 + 1];
        *(short8*)(lx + swz(tb, tc * 64 + u * 16)) = pack8(a, b);
      }
      __syncthreads();
      acc_main[0] = 0.f; acc_main[1] = 0.f; acc_main[2] = 0.f; acc_main[3] = 0.f;
      if (wv < 3) {
        char* wrow = smem + OFF_WIH + wv * 16384 + lrow * 1024;
        char* xr   = smem + OFF_X + lrow * 1024;
        #pragma unroll
        for (int kc = 0; kc < 16; ++kc) {
          short8 a = *(const short8*)(xr   + swz(lrow, kc * 64 + q * 16));
          short8 b = *(const short8*)(wrow + swz(lrow, kc * 64 + q * 16));
          acc_main = __builtin_amdgcn_mfma_f32_16x16x32_bf16(a, b, acc_main, 0, 0, 0);
        }
      }
    }
  }

  // layer 1: flush the last delayed output (after everyone consumed x(p_{T-1}))
  if (LAYER == 1) {
    if (tid < 32) {
      const unsigned tgt = (unsigned)(T_LEN + 1);
      while (__hip_atomic_load(&fl[tid], __ATOMIC_RELAXED, __HIP_MEMORY_SCOPE_AGENT) < tgt)
        __builtin_amdgcn_s_sleep(1);
    }
    __syncthreads();
    const int tlast = dir ? 0 : (T_LEN - 1);
    dout[(size_t)bglobal * T_LEN * 2 * H_DIM + (size_t)tlast * 2 * H_DIM + dircol + hcol] = yprev;
  }
}

extern "C" void kernel_launch(void* const* d_in, const int* in_sizes, int n_in,
                              void* d_out, int out_size, void* d_ws, size_t ws_size,
                              hipStream_t stream) {
  (void)in_sizes; (void)n_in; (void)out_size; (void)ws_size;
  const float* x    = (const float*)d_in[0];
  const float* enc  = (const float*)d_in[1];
  const float* WihF = (const float*)d_in[2];
  const float* WhhF = (const float*)d_in[3];
  const float* bihF = (const float*)d_in[4];
  const float* bhhF = (const float*)d_in[5];
  const float* WihB = (const float*)d_in[6];
  const float* WhhB = (const float*)d_in[7];
  const float* bihB = (const float*)d_in[8];
  const float* bhhB = (const float*)d_in[9];
  float* out = (float*)d_out;

  unsigned* flags = (unsigned*)d_ws;                      // 16 groups x 256B
  unsigned short* hbuf = (unsigned short*)((char*)d_ws + 4096);
  hipMemsetAsync(d_ws, 0, 4096, stream);                  // zero flags each replay

  dim3 grid(GROUP * 8), block(256);
  gru_layer<0><<<grid, block, 0, stream>>>(x, enc, WihF, WhhF, bihF, bhhF,
                                           WihB, WhhB, bihB, bhhB, out, flags, hbuf);
  gru_layer<1><<<grid, block, 0, stream>>>(x, enc, WihF, WhhF, bihF, bhhF,
                                           WihB, WhhB, bihB, bhhB, out, flags, hbuf);
}